// Round 15
// baseline (602.776 us; speedup 1.0000x reference)
//
#include <hip/hip_runtime.h>
#include <hip/hip_fp16.h>
#include <math.h>

// ---------------------------------------------------------------------------
// GAT 4-layer forward.  (R15 = R14 + B-direct gemm: B frags from global)
//   R14 model: gemm is LDS-read-BW bound (16 KB LDS reads per 32 MFMAs per
//   wave-iter vs 128 B/cyc/CU). Fix: B (=W^T, <=0.5 MB, L1/L2-resident,
//   K-contiguous) is read as per-lane 16B dwordx4 MFMA fragments DIRECTLY
//   from global -- only A is staged in LDS (16 KB). Halves LDS traffic/MAC.
//   All operands fp16 (R13: fp16-weight error below harness bf16-ref floor).
//   agg at its pattern ceiling (8-XCD compulsory fill @ ~3.6 TB/s).
// ---------------------------------------------------------------------------

typedef __attribute__((ext_vector_type(8))) _Float16 f16x8;
typedef __attribute__((ext_vector_type(4))) float floatx4;
typedef __attribute__((ext_vector_type(8))) unsigned short usv8;
typedef __attribute__((ext_vector_type(4))) unsigned short usv4;

#define DEG_CAP 256

__device__ __forceinline__ float lrelu(float e) {
    return (e > 0.f) ? e : 0.2f * e;
}
__device__ __forceinline__ void gload16(const void* g, void* l) {
    __builtin_amdgcn_global_load_lds(
        (const __attribute__((address_space(1))) void*)g,
        (__attribute__((address_space(3))) void*)l, 16, 0, 0);
}

// ---------------------------------------------------------------------------
// CSR build
// ---------------------------------------------------------------------------
static __global__ void zero_int(int* __restrict__ p, int n) {
    int i = blockIdx.x * blockDim.x + threadIdx.x;
    if (i < n) p[i] = 0;
}

static __global__ void hist_kernel(const int* __restrict__ ei, int e0, int n_nodes,
                                   int* __restrict__ counts) {
    int e = blockIdx.x * blockDim.x + threadIdx.x;
    int et = e0 + n_nodes;
    if (e >= et) return;
    int d = (e < e0) ? ei[e0 + e] : (e - e0);
    atomicAdd(&counts[d], 1);
}

static __global__ void scan_kernel(const int* __restrict__ counts,
                                   int* __restrict__ row_ptr,
                                   int* __restrict__ cursor, int n) {
    __shared__ int sdata[1024];
    int tid = threadIdx.x;
    int per = (n + 1023) / 1024;
    int start = tid * per;
    int stop = min(start + per, n);
    if (start > n) start = n;
    int s = 0;
    for (int i = start; i < stop; i++) s += counts[i];
    sdata[tid] = s;
    __syncthreads();
    for (int off = 1; off < 1024; off <<= 1) {
        int t = (tid >= off) ? sdata[tid - off] : 0;
        __syncthreads();
        sdata[tid] += t;
        __syncthreads();
    }
    int run = sdata[tid] - s;
    for (int i = start; i < stop; i++) {
        row_ptr[i] = run;
        cursor[i] = run;
        run += counts[i];
    }
    if (stop == n) row_ptr[n] = run;
}

static __global__ void scatter_kernel(const int* __restrict__ ei, int e0, int n_nodes,
                                      int* __restrict__ cursor,
                                      int* __restrict__ src_sorted) {
    int e = blockIdx.x * blockDim.x + threadIdx.x;
    int et = e0 + n_nodes;
    if (e >= et) return;
    int s, d;
    if (e < e0) { s = ei[e]; d = ei[e0 + e]; } else { s = e - e0; d = s; }
    int pos = atomicAdd(&cursor[d], 1);
    src_sorted[pos] = s;
}

// ---------------------------------------------------------------------------
// conversions. A = fp16 round of x. BT[Npad,K] fp16 = W^T. Also zeroes as/ad.
// ---------------------------------------------------------------------------
static __global__ void convA_kernel(const float* __restrict__ X,
                                    __half* __restrict__ A, int total) {
    int idx = blockIdx.x * 256 + threadIdx.x;
    if (idx >= total) return;
    A[idx] = __float2half(X[idx]);
}

__device__ __forceinline__ void convW_one(const float* W, __half* BT,
                                          int idx, int K, int N) {
    int n = idx / K, k = idx % K;
    float v = (n < N) ? W[(size_t)k * N + n] : 0.f;
    BT[(size_t)n * K + k] = __float2half(v);
}

static __global__ void convW_all(const float* __restrict__ W1, __half* __restrict__ BT1,
                                 const float* __restrict__ W2, __half* __restrict__ BT2,
                                 const float* __restrict__ W3, __half* __restrict__ BT3,
                                 const float* __restrict__ W4, __half* __restrict__ BT4,
                                 float* __restrict__ zero_as, int nzero) {
    int idx = blockIdx.x * 256 + threadIdx.x;
    if (idx < 131072) { convW_one(W1, BT1, idx, 256, 512); return; }
    idx -= 131072;
    if (idx < 262144) { convW_one(W2, BT2, idx, 512, 512); return; }
    idx -= 262144;
    if (idx < 131072) { convW_one(W3, BT3, idx, 512, 256); return; }
    idx -= 131072;
    if (idx < 32768)  { convW_one(W4, BT4, idx, 256, 64); return; }
    idx -= 32768;
    if (idx < nzero) zero_as[idx] = 0.f;
}

// ---------------------------------------------------------------------------
// fp16 MFMA GEMM: C = A_f16 x B_f16. BKK=64. A staged in 16 KB LDS (XOR
// swizzle); B fragments loaded per-lane dwordx4 DIRECTLY from global
// (K-contiguous BT rows; L1/L2-resident). XCD-aware 1-D swizzle, fused
// alpha epilogue, fp16 C.
// ---------------------------------------------------------------------------
#define BM 128
#define BN 128
#define BKK 64

__launch_bounds__(256, 4)
static __global__ void gemm_mfma(const __half* __restrict__ A,
                                 const __half* __restrict__ B,
                                 __half* __restrict__ C, int M, int K, int N,
                                 int xcols, int mblocks,
                                 const float* __restrict__ asv,
                                 const float* __restrict__ adv,
                                 float* __restrict__ as_out,
                                 float* __restrict__ ad_out,
                                 int Hh, int Cc) {
    __shared__ __align__(16) __half lds[BM * BKK];   // 16 KB (A only)
    const int tid  = threadIdx.x;
    const int lane = tid & 63;
    const int wave = tid >> 6;

    const int id = blockIdx.x;
    const int band = id / (8 * xcols);
    const int rem = id - band * 8 * xcols;
    const int band_rows = min(8, mblocks - band * 8);
    const int ry = rem % band_rows;
    const int rx = rem / band_rows;
    const int r0 = (band * 8 + ry) * BM;
    const int c0 = rx * BN;

    const int wm = (wave >> 1) * 64;
    const int wn = (wave & 1) * 64;
    const int q   = lane >> 4;        // 0..3
    const int m16 = lane & 15;

    floatx4 acc[4][4];
#pragma unroll
    for (int i = 0; i < 4; i++)
#pragma unroll
        for (int j = 0; j < 4; j++) acc[i][j] = {0.f, 0.f, 0.f, 0.f};

    char* ldsb = (char*)lds;

    // B fragment row pointers (fixed across K)
    const __half* brow[4];
#pragma unroll
    for (int j = 0; j < 4; j++)
        brow[j] = B + (size_t)(c0 + wn + j * 16 + m16) * K;

#pragma unroll 1
    for (int k0 = 0; k0 < K; k0 += BKK) {
        __syncthreads();
#pragma unroll
        for (int c = 0; c < 4; c++) {
            int slot = c * 256 + tid;      // 0..1023
            int row = slot >> 3;           // 0..127
            int gc  = (slot & 7) ^ (row & 7);
            gload16(A + (size_t)(r0 + row) * K + k0 + gc * 8,
                    ldsb + slot * 16);
        }
        __syncthreads();
#pragma unroll
        for (int ks = 0; ks < 2; ks++) {
            f16x8 bf[4];
#pragma unroll
            for (int j = 0; j < 4; j++)
                bf[j] = *(const f16x8*)(brow[j] + k0 + (q + ks * 4) * 8);
            f16x8 af[4];
#pragma unroll
            for (int i = 0; i < 4; i++) {
                int row = wm + i * 16 + m16;
                int ch  = (q + ks * 4) ^ (row & 7);
                af[i] = *(const f16x8*)(ldsb + (row * 8 + ch) * 16);
            }
#pragma unroll
            for (int i = 0; i < 4; i++)
#pragma unroll
                for (int j = 0; j < 4; j++)
                    acc[i][j] = __builtin_amdgcn_mfma_f32_16x16x32_f16(
                        af[i], bf[j], acc[i][j], 0, 0, 0);
        }
    }
    // C store (fp16). C/D layout: col = lane&15, row = (lane>>4)*4 + reg
#pragma unroll
    for (int i = 0; i < 4; i++)
#pragma unroll
        for (int j = 0; j < 4; j++)
#pragma unroll
            for (int r = 0; r < 4; r++) {
                int row = r0 + wm + i * 16 + q * 4 + r;
                int col = c0 + wn + j * 16 + m16;
                if (row < M && col < N)
                    C[(size_t)row * N + col] = __float2half(acc[i][j][r]);
            }
    // fused alpha epilogue: wave's 64-col chunk is head-uniform (C in {64,128}).
    if (c0 + wn < N) {
        int head = (c0 + wn) / Cc;
#pragma unroll
        for (int i = 0; i < 4; i++)
#pragma unroll
            for (int r = 0; r < 4; r++) {
                float ps = 0.f, pd = 0.f;
#pragma unroll
                for (int j = 0; j < 4; j++) {
                    int c = c0 + wn + j * 16 + m16;
                    float v = acc[i][j][r];
                    ps = fmaf(v, asv[c], ps);
                    pd = fmaf(v, adv[c], pd);
                }
#pragma unroll
                for (int off = 1; off < 16; off <<= 1) {
                    ps += __shfl_xor(ps, off);
                    pd += __shfl_xor(pd, off);
                }
                if (m16 == 0) {
                    int row = r0 + wm + i * 16 + q * 4 + r;
                    if (row < M) {
                        atomicAdd(&as_out[(size_t)row * Hh + head], ps);
                        atomicAdd(&ad_out[(size_t)row * Hh + head], pd);
                    }
                }
            }
    }
}

// ---------------------------------------------------------------------------
// gather helper: acc[r] += w * h_fp16[off+r]
// ---------------------------------------------------------------------------
template <int R>
__device__ __forceinline__ void accum_row(const __half* hptr, size_t off, float w,
                                          float* acc) {
    const __half* p = hptr + off;
    if constexpr (R == 8) {
        float4 raw = *(const float4*)p;          // 8 halves, one dwordx4
        const __half* hv = (const __half*)&raw;
#pragma unroll
        for (int r = 0; r < 8; r++) acc[r] = fmaf(__half2float(hv[r]), w, acc[r]);
    } else if constexpr (R == 4) {
        float2 raw = *(const float2*)p;
        const __half* hv = (const __half*)&raw;
#pragma unroll
        for (int r = 0; r < 4; r++) acc[r] = fmaf(__half2float(hv[r]), w, acc[r]);
    } else {
        acc[0] = fmaf(__half2float(*p), w, acc[0]);
    }
}

// ---------------------------------------------------------------------------
// aggregation: one wave/node. Pass 1 caches e in LDS (DEG_CAP), reduces m,l.
// Pass 2: 4-edge unroll, w from cached e, fp16 gather. Output fp16 (next A)
// or fp32 (final). Epilogue zeroes next layer's as/ad ping-pong.
// ---------------------------------------------------------------------------
template <int H, int C, bool F16OUT>
__launch_bounds__(256)
static __global__ void agg_kernel(const __half* __restrict__ h,
                                  const float* __restrict__ as_arr,
                                  const float* __restrict__ ad_arr,
                                  const int* __restrict__ row_ptr,
                                  const int* __restrict__ src_sorted,
                                  const float* __restrict__ bias,
                                  float* __restrict__ outf,
                                  __half* __restrict__ outh,
                                  float* __restrict__ znext_as,
                                  float* __restrict__ znext_ad, int n_nodes) {
    constexpr int R = H * C / 64;
    constexpr int G = 64 / H;
    constexpr int K = H * C;
    __shared__ float lds_e[4][DEG_CAP * H];
    int wave = threadIdx.x >> 6;
    int lane = threadIdx.x & 63;
    int n = blockIdx.x * 4 + wave;
    if (n >= n_nodes) return;
    int beg = row_ptr[n], end = row_ptr[n + 1];
    float* we = lds_e[wave];

    // ---- pass 1: per-head m, l; cache e in LDS ----
    float ad_h[H], m_h[H], l_h[H];
#pragma unroll
    for (int hh = 0; hh < H; hh++) {
        ad_h[hh] = ad_arr[(size_t)n * H + hh];
        m_h[hh] = -INFINITY;
        l_h[hh] = 0.f;
    }
    for (int base = beg; base < end; base += 64) {
        int j = base + lane;
        bool ok = j < end;
        float e_h[H];
        if (ok) {
            int s = src_sorted[j];
            if constexpr (H == 4) {
                float4 a = ((const float4*)as_arr)[s];
                e_h[0] = lrelu(a.x + ad_h[0]);
                e_h[1] = lrelu(a.y + ad_h[1]);
                e_h[2] = lrelu(a.z + ad_h[2]);
                e_h[3] = lrelu(a.w + ad_h[3]);
            } else {
                e_h[0] = lrelu(as_arr[s] + ad_h[0]);
            }
            int idx = j - beg;
            if (idx < DEG_CAP) {
                if constexpr (H == 4) {
                    *(float4*)&we[idx * 4] = make_float4(e_h[0], e_h[1], e_h[2], e_h[3]);
                } else {
                    we[idx] = e_h[0];
                }
            }
        } else {
#pragma unroll
            for (int hh = 0; hh < H; hh++) e_h[hh] = -INFINITY;
        }
#pragma unroll
        for (int hh = 0; hh < H; hh++) {
            float cm = e_h[hh];
#pragma unroll
            for (int off = 1; off < 64; off <<= 1) cm = fmaxf(cm, __shfl_xor(cm, off));
            float newm = fmaxf(m_h[hh], cm);
            float p = ok ? __expf(e_h[hh] - newm) : 0.f;
#pragma unroll
            for (int off = 1; off < 64; off <<= 1) p += __shfl_xor(p, off);
            l_h[hh] = l_h[hh] * __expf(m_h[hh] - newm) + p;
            m_h[hh] = newm;
        }
    }
    int myh = lane / G;
    float mm, adm, inv;
    if constexpr (H == 4) {
        mm  = m_h[0];  mm  = (myh == 1) ? m_h[1] : mm;  mm  = (myh == 2) ? m_h[2] : mm;  mm  = (myh == 3) ? m_h[3] : mm;
        float ll = l_h[0]; ll = (myh == 1) ? l_h[1] : ll; ll = (myh == 2) ? l_h[2] : ll; ll = (myh == 3) ? l_h[3] : ll;
        adm = ad_h[0]; adm = (myh == 1) ? ad_h[1] : adm; adm = (myh == 2) ? ad_h[2] : adm; adm = (myh == 3) ? ad_h[3] : adm;
        inv = 1.f / ll;
    } else {
        mm = m_h[0]; adm = ad_h[0]; inv = 1.f / l_h[0];
    }

    // ---- pass 2: gather, w from cached e (4-edge unroll) ----
    float acc[R];
#pragma unroll
    for (int r = 0; r < R; r++) acc[r] = 0.f;

    int j = beg;
    for (; j + 3 < end; j += 4) {
        int i0 = j - beg;
        int s0 = src_sorted[j];
        int s1 = src_sorted[j + 1];
        int s2 = src_sorted[j + 2];
        int s3 = src_sorted[j + 3];
        float e0, e1, e2, e3;
        if (i0 + 3 < DEG_CAP) {
            e0 = we[(i0 + 0) * H + myh];
            e1 = we[(i0 + 1) * H + myh];
            e2 = we[(i0 + 2) * H + myh];
            e3 = we[(i0 + 3) * H + myh];
        } else {
            e0 = lrelu(as_arr[(size_t)s0 * H + myh] + adm);
            e1 = lrelu(as_arr[(size_t)s1 * H + myh] + adm);
            e2 = lrelu(as_arr[(size_t)s2 * H + myh] + adm);
            e3 = lrelu(as_arr[(size_t)s3 * H + myh] + adm);
        }
        float w0 = __expf(e0 - mm) * inv;
        float w1 = __expf(e1 - mm) * inv;
        float w2 = __expf(e2 - mm) * inv;
        float w3 = __expf(e3 - mm) * inv;
        accum_row<R>(h, (size_t)s0 * K + lane * R, w0, acc);
        accum_row<R>(h, (size_t)s1 * K + lane * R, w1, acc);
        accum_row<R>(h, (size_t)s2 * K + lane * R, w2, acc);
        accum_row<R>(h, (size_t)s3 * K + lane * R, w3, acc);
    }
    for (; j < end; j++) {
        int i0 = j - beg;
        int s0 = src_sorted[j];
        float e0 = (i0 < DEG_CAP) ? we[i0 * H + myh]
                                  : lrelu(as_arr[(size_t)s0 * H + myh] + adm);
        float w0 = __expf(e0 - mm) * inv;
        accum_row<R>(h, (size_t)s0 * K + lane * R, w0, acc);
    }

    // ---- epilogue: bias + relu; zero next layer's as/ad ----
    if (znext_as != nullptr && lane == 0) {
        if constexpr (H == 4) {
            *(float4*)&znext_as[(size_t)n * 4] = make_float4(0.f, 0.f, 0.f, 0.f);
            *(float4*)&znext_ad[(size_t)n * 4] = make_float4(0.f, 0.f, 0.f, 0.f);
        } else {
            znext_as[n] = 0.f;
            znext_ad[n] = 0.f;
        }
    }
    float vout[R];
#pragma unroll
    for (int r = 0; r < R; r++)
        vout[r] = fmaxf(acc[r] + bias[lane * R + r], 0.f);

    if constexpr (F16OUT) {
        unsigned short hv[R];
#pragma unroll
        for (int r = 0; r < R; r++)
            hv[r] = __half_as_ushort(__float2half(vout[r]));
        size_t base = (size_t)n * K + lane * R;
        if constexpr (R == 8) {
            usv8 v = {hv[0], hv[1], hv[2], hv[3], hv[4], hv[5], hv[6], hv[7]};
            *(usv8*)((unsigned short*)outh + base) = v;
        } else if constexpr (R == 4) {
            usv4 v = {hv[0], hv[1], hv[2], hv[3]};
            *(usv4*)((unsigned short*)outh + base) = v;
        } else {
#pragma unroll
            for (int r = 0; r < R; r++) ((unsigned short*)outh)[base + r] = hv[r];
        }
    } else {
#pragma unroll
        for (int r = 0; r < R; r++)
            outf[(size_t)n * K + lane * R + r] = vout[r];
    }
}

// ---------------------------------------------------------------------------

static inline size_t align_up(size_t x) { return (x + 255) & ~(size_t)255; }

extern "C" void kernel_launch(void* const* d_in, const int* in_sizes, int n_in,
                              void* d_out, int out_size, void* d_ws, size_t ws_size,
                              hipStream_t stream) {
    const float* x   = (const float*)d_in[0];
    const int*   ei  = (const int*)d_in[1];
    const float* W1  = (const float*)d_in[2];
    const float* a1s = (const float*)d_in[3];
    const float* a1d = (const float*)d_in[4];
    const float* b1  = (const float*)d_in[5];
    const float* W2  = (const float*)d_in[6];
    const float* a2s = (const float*)d_in[7];
    const float* a2d = (const float*)d_in[8];
    const float* b2  = (const float*)d_in[9];
    const float* W3  = (const float*)d_in[10];
    const float* a3s = (const float*)d_in[11];
    const float* a3d = (const float*)d_in[12];
    const float* b3  = (const float*)d_in[13];
    const float* W4  = (const float*)d_in[14];
    const float* a4s = (const float*)d_in[15];
    const float* a4d = (const float*)d_in[16];
    const float* b4  = (const float*)d_in[17];

    const int n  = in_sizes[0] / 256;    // 30000
    const int e0 = in_sizes[1] / 2;      // 480000
    const int et = e0 + n;
    const int Mpad = ((n + 127) / 128) * 128;   // 30080

    // workspace layout (~100 MB)
    char* w = (char*)d_ws;
    __half* bufA = (__half*)w;                   w += align_up((size_t)Mpad * 512 * 2);
    __half* bufB = (__half*)w;                   w += align_up((size_t)Mpad * 512 * 2);
    __half* hbuf = (__half*)w;                   w += align_up((size_t)Mpad * 512 * 2);
    __half* WT1 = (__half*)w;                    w += align_up((size_t)512 * 256 * 2);
    __half* WT2 = (__half*)w;                    w += align_up((size_t)512 * 512 * 2);
    __half* WT3 = (__half*)w;                    w += align_up((size_t)256 * 512 * 2);
    __half* WT4 = (__half*)w;                    w += align_up((size_t)128 * 256 * 2);
    float* asA = (float*)w;                      w += align_up((size_t)n * 4 * 4);
    float* adA = (float*)w;                      w += align_up((size_t)n * 4 * 4);
    float* asB = (float*)w;                      w += align_up((size_t)n * 4 * 4);
    float* adB = (float*)w;                      w += align_up((size_t)n * 4 * 4);
    int* row_ptr = (int*)w;                      w += align_up((size_t)(n + 1) * 4);
    int* counts  = (int*)w;                      w += align_up((size_t)n * 4);
    int* cursor  = (int*)w;                      w += align_up((size_t)n * 4);
    int* src_sorted = (int*)w;                   w += align_up((size_t)et * 4);
    (void)ws_size;

    dim3 blk(256);
    int nodeblocks = (n + 3) / 4;

    // ---- CSR build ----
    zero_int<<<(n + 255) / 256, 256, 0, stream>>>(counts, n);
    hist_kernel<<<(et + 255) / 256, 256, 0, stream>>>(ei, e0, n, counts);
    scan_kernel<<<1, 1024, 0, stream>>>(counts, row_ptr, cursor, n);
    scatter_kernel<<<(et + 255) / 256, 256, 0, stream>>>(ei, e0, n, cursor, src_sorted);

    // ---- operand conversion (+ zero of layer-1 as/ad, fused) ----
    convA_kernel<<<((n * 256) + 255) / 256, blk, 0, stream>>>(x, bufA, n * 256);
    convW_all<<<(557056 + n * 8 + 255) / 256, blk, 0, stream>>>(W1, WT1, W2, WT2, W3, WT3, W4, WT4, asA, n * 8);

    const int mblocks = Mpad / 128;   // 235

    // ---- Layer 1: K=256 -> N=512 (4 heads x 128) ----
    gemm_mfma<<<dim3(4 * mblocks), blk, 0, stream>>>(bufA, WT1, hbuf, n, 256, 512, 4, mblocks,
                                                     a1s, a1d, asA, adA, 4, 128);
    agg_kernel<4, 128, true><<<nodeblocks, blk, 0, stream>>>(hbuf, asA, adA, row_ptr, src_sorted, b1, nullptr, bufB, asB, adB, n);

    // ---- Layer 2: K=512 -> N=512 ----
    gemm_mfma<<<dim3(4 * mblocks), blk, 0, stream>>>(bufB, WT2, hbuf, n, 512, 512, 4, mblocks,
                                                     a2s, a2d, asB, adB, 4, 128);
    agg_kernel<4, 128, true><<<nodeblocks, blk, 0, stream>>>(hbuf, asB, adB, row_ptr, src_sorted, b2, nullptr, bufA, asA, adA, n);

    // ---- Layer 3: K=512 -> N=256 (4 heads x 64) ----
    gemm_mfma<<<dim3(2 * mblocks), blk, 0, stream>>>(bufA, WT3, hbuf, n, 512, 256, 2, mblocks,
                                                     a3s, a3d, asA, adA, 4, 64);
    agg_kernel<4, 64, true><<<nodeblocks, blk, 0, stream>>>(hbuf, asA, adA, row_ptr, src_sorted, b3, nullptr, bufB, asB, adB, n);

    // ---- Layer 4: K=256 -> N=64, 1 head ----
    gemm_mfma<<<dim3(1 * mblocks), blk, 0, stream>>>(bufB, WT4, hbuf, n, 256, 64, 1, mblocks,
                                                     a4s, a4d, asB, adB, 1, 64);
    agg_kernel<1, 64, false><<<nodeblocks, blk, 0, stream>>>(hbuf, asB, adB, row_ptr, src_sorted, b4, (float*)d_out, nullptr, nullptr, nullptr, n);
}

// Round 16
// 563.007 us; speedup vs baseline: 1.0706x; 1.0706x over previous
//
#include <hip/hip_runtime.h>
#include <hip/hip_fp16.h>
#include <math.h>

// ---------------------------------------------------------------------------
// GAT 4-layer forward.  (R16 = R14 revert + fused conv prologue)
//   R15 lesson: B-direct-from-global regressed (+38us) -- per-lane B frags
//   stride K*2 bytes so each 16-lane group hits 16 cache lines/load; LDS's
//   value is address regularization, not just bytes. R14 config restored:
//   GEMM C = A_f16 x B_f16, BKK=64, 32 KB LDS (A|B), 32 MFMAs/barrier,
//   XCD swizzle, fused alpha epilogue, fp16 C.
//   agg: pass-1 softmax stats with LDS e-cache, pass-2 4-edge fp16 gather
//   (pattern ceiling: 8-XCD x 30 MB compulsory fill @ ~3.6 TB/s random-line
//   rate), fp16 out, zeroes next as/ad ping-pong.
//   Conv prologue fused into ONE dispatch (x->fp16 + 4x W^T + as/ad zero).
// ---------------------------------------------------------------------------

typedef __attribute__((ext_vector_type(8))) _Float16 f16x8;
typedef __attribute__((ext_vector_type(4))) float floatx4;
typedef __attribute__((ext_vector_type(8))) unsigned short usv8;
typedef __attribute__((ext_vector_type(4))) unsigned short usv4;

#define DEG_CAP 256

__device__ __forceinline__ float lrelu(float e) {
    return (e > 0.f) ? e : 0.2f * e;
}
__device__ __forceinline__ void gload16(const void* g, void* l) {
    __builtin_amdgcn_global_load_lds(
        (const __attribute__((address_space(1))) void*)g,
        (__attribute__((address_space(3))) void*)l, 16, 0, 0);
}

// ---------------------------------------------------------------------------
// CSR build
// ---------------------------------------------------------------------------
static __global__ void zero_int(int* __restrict__ p, int n) {
    int i = blockIdx.x * blockDim.x + threadIdx.x;
    if (i < n) p[i] = 0;
}

static __global__ void hist_kernel(const int* __restrict__ ei, int e0, int n_nodes,
                                   int* __restrict__ counts) {
    int e = blockIdx.x * blockDim.x + threadIdx.x;
    int et = e0 + n_nodes;
    if (e >= et) return;
    int d = (e < e0) ? ei[e0 + e] : (e - e0);
    atomicAdd(&counts[d], 1);
}

static __global__ void scan_kernel(const int* __restrict__ counts,
                                   int* __restrict__ row_ptr,
                                   int* __restrict__ cursor, int n) {
    __shared__ int sdata[1024];
    int tid = threadIdx.x;
    int per = (n + 1023) / 1024;
    int start = tid * per;
    int stop = min(start + per, n);
    if (start > n) start = n;
    int s = 0;
    for (int i = start; i < stop; i++) s += counts[i];
    sdata[tid] = s;
    __syncthreads();
    for (int off = 1; off < 1024; off <<= 1) {
        int t = (tid >= off) ? sdata[tid - off] : 0;
        __syncthreads();
        sdata[tid] += t;
        __syncthreads();
    }
    int run = sdata[tid] - s;
    for (int i = start; i < stop; i++) {
        row_ptr[i] = run;
        cursor[i] = run;
        run += counts[i];
    }
    if (stop == n) row_ptr[n] = run;
}

static __global__ void scatter_kernel(const int* __restrict__ ei, int e0, int n_nodes,
                                      int* __restrict__ cursor,
                                      int* __restrict__ src_sorted) {
    int e = blockIdx.x * blockDim.x + threadIdx.x;
    int et = e0 + n_nodes;
    if (e >= et) return;
    int s, d;
    if (e < e0) { s = ei[e]; d = ei[e0 + e]; } else { s = e - e0; d = s; }
    int pos = atomicAdd(&cursor[d], 1);
    src_sorted[pos] = s;
}

// ---------------------------------------------------------------------------
// fused conversion prologue: x -> fp16 A, 4x W -> fp16 W^T, zero as/ad.
// ---------------------------------------------------------------------------
__device__ __forceinline__ void convW_one(const float* W, __half* BT,
                                          int idx, int K, int N) {
    int n = idx / K, k = idx % K;
    float v = (n < N) ? W[(size_t)k * N + n] : 0.f;
    BT[(size_t)n * K + k] = __float2half(v);
}

static __global__ void conv_all(const float* __restrict__ X, __half* __restrict__ A, int nx,
                                const float* __restrict__ W1, __half* __restrict__ BT1,
                                const float* __restrict__ W2, __half* __restrict__ BT2,
                                const float* __restrict__ W3, __half* __restrict__ BT3,
                                const float* __restrict__ W4, __half* __restrict__ BT4,
                                float* __restrict__ zero_as, int nzero) {
    int idx = blockIdx.x * 256 + threadIdx.x;
    if (idx < nx) { A[idx] = __float2half(X[idx]); return; }
    idx -= nx;
    if (idx < 131072) { convW_one(W1, BT1, idx, 256, 512); return; }
    idx -= 131072;
    if (idx < 262144) { convW_one(W2, BT2, idx, 512, 512); return; }
    idx -= 262144;
    if (idx < 131072) { convW_one(W3, BT3, idx, 512, 256); return; }
    idx -= 131072;
    if (idx < 32768)  { convW_one(W4, BT4, idx, 256, 64); return; }
    idx -= 32768;
    if (idx < nzero) zero_as[idx] = 0.f;
}

// ---------------------------------------------------------------------------
// fp16 MFMA GEMM: C = A_f16 x B_f16. BKK=64, 32 KB LDS (A|B), 32 MFMAs per
// barrier, XCD-aware 1-D swizzle, fused alpha epilogue, fp16 C.
// Bank swizzle: 8 chunks/row, XOR with row&7.
// ---------------------------------------------------------------------------
#define BM 128
#define BN 128
#define BKK 64

__launch_bounds__(256, 4)
static __global__ void gemm_mfma(const __half* __restrict__ A,
                                 const __half* __restrict__ B,
                                 __half* __restrict__ C, int M, int K, int N,
                                 int xcols, int mblocks,
                                 const float* __restrict__ asv,
                                 const float* __restrict__ adv,
                                 float* __restrict__ as_out,
                                 float* __restrict__ ad_out,
                                 int Hh, int Cc) {
    __shared__ __align__(16) __half lds[2 * BM * BKK];   // 32 KB
    const int tid  = threadIdx.x;
    const int lane = tid & 63;
    const int wave = tid >> 6;

    const int id = blockIdx.x;
    const int band = id / (8 * xcols);
    const int rem = id - band * 8 * xcols;
    const int band_rows = min(8, mblocks - band * 8);
    const int ry = rem % band_rows;
    const int rx = rem / band_rows;
    const int r0 = (band * 8 + ry) * BM;
    const int c0 = rx * BN;

    const int wm = (wave >> 1) * 64;
    const int wn = (wave & 1) * 64;
    const int q   = lane >> 4;        // 0..3
    const int m16 = lane & 15;

    floatx4 acc[4][4];
#pragma unroll
    for (int i = 0; i < 4; i++)
#pragma unroll
        for (int j = 0; j < 4; j++) acc[i][j] = {0.f, 0.f, 0.f, 0.f};

    char* ldsb = (char*)lds;

#pragma unroll 1
    for (int k0 = 0; k0 < K; k0 += BKK) {
        __syncthreads();
#pragma unroll
        for (int c = 0; c < 4; c++) {
            int slot = c * 256 + tid;      // 0..1023
            int row = slot >> 3;           // 0..127
            int gc  = (slot & 7) ^ (row & 7);
            gload16(A + (size_t)(r0 + row) * K + k0 + gc * 8,
                    ldsb + slot * 16);                       // A
            gload16(B + (size_t)(c0 + row) * K + k0 + gc * 8,
                    ldsb + 16384 + slot * 16);               // B
        }
        __syncthreads();
#pragma unroll
        for (int ks = 0; ks < 2; ks++) {
            f16x8 af[4], bf[4];
#pragma unroll
            for (int i = 0; i < 4; i++) {
                int row = wm + i * 16 + m16;
                int ch  = (q + ks * 4) ^ (row & 7);
                af[i] = *(const f16x8*)(ldsb + (row * 8 + ch) * 16);
            }
#pragma unroll
            for (int j = 0; j < 4; j++) {
                int row = wn + j * 16 + m16;
                int ch  = (q + ks * 4) ^ (row & 7);
                bf[j] = *(const f16x8*)(ldsb + 16384 + (row * 8 + ch) * 16);
            }
#pragma unroll
            for (int i = 0; i < 4; i++)
#pragma unroll
                for (int j = 0; j < 4; j++)
                    acc[i][j] = __builtin_amdgcn_mfma_f32_16x16x32_f16(
                        af[i], bf[j], acc[i][j], 0, 0, 0);
        }
    }
    // C store (fp16). C/D layout: col = lane&15, row = (lane>>4)*4 + reg
#pragma unroll
    for (int i = 0; i < 4; i++)
#pragma unroll
        for (int j = 0; j < 4; j++)
#pragma unroll
            for (int r = 0; r < 4; r++) {
                int row = r0 + wm + i * 16 + q * 4 + r;
                int col = c0 + wn + j * 16 + m16;
                if (row < M && col < N)
                    C[(size_t)row * N + col] = __float2half(acc[i][j][r]);
            }
    // fused alpha epilogue: wave's 64-col chunk is head-uniform (C in {64,128}).
    if (c0 + wn < N) {
        int head = (c0 + wn) / Cc;
#pragma unroll
        for (int i = 0; i < 4; i++)
#pragma unroll
            for (int r = 0; r < 4; r++) {
                float ps = 0.f, pd = 0.f;
#pragma unroll
                for (int j = 0; j < 4; j++) {
                    int c = c0 + wn + j * 16 + m16;
                    float v = acc[i][j][r];
                    ps = fmaf(v, asv[c], ps);
                    pd = fmaf(v, adv[c], pd);
                }
#pragma unroll
                for (int off = 1; off < 16; off <<= 1) {
                    ps += __shfl_xor(ps, off);
                    pd += __shfl_xor(pd, off);
                }
                if (m16 == 0) {
                    int row = r0 + wm + i * 16 + q * 4 + r;
                    if (row < M) {
                        atomicAdd(&as_out[(size_t)row * Hh + head], ps);
                        atomicAdd(&ad_out[(size_t)row * Hh + head], pd);
                    }
                }
            }
    }
}

// ---------------------------------------------------------------------------
// gather helper: acc[r] += w * h_fp16[off+r]
// ---------------------------------------------------------------------------
template <int R>
__device__ __forceinline__ void accum_row(const __half* hptr, size_t off, float w,
                                          float* acc) {
    const __half* p = hptr + off;
    if constexpr (R == 8) {
        float4 raw = *(const float4*)p;          // 8 halves, one dwordx4
        const __half* hv = (const __half*)&raw;
#pragma unroll
        for (int r = 0; r < 8; r++) acc[r] = fmaf(__half2float(hv[r]), w, acc[r]);
    } else if constexpr (R == 4) {
        float2 raw = *(const float2*)p;
        const __half* hv = (const __half*)&raw;
#pragma unroll
        for (int r = 0; r < 4; r++) acc[r] = fmaf(__half2float(hv[r]), w, acc[r]);
    } else {
        acc[0] = fmaf(__half2float(*p), w, acc[0]);
    }
}

// ---------------------------------------------------------------------------
// aggregation: one wave/node. Pass 1 caches e in LDS (DEG_CAP), reduces m,l.
// Pass 2: 4-edge unroll, w from cached e, fp16 gather. Output fp16 (next A)
// or fp32 (final). Epilogue zeroes next layer's as/ad ping-pong.
// ---------------------------------------------------------------------------
template <int H, int C, bool F16OUT>
__launch_bounds__(256)
static __global__ void agg_kernel(const __half* __restrict__ h,
                                  const float* __restrict__ as_arr,
                                  const float* __restrict__ ad_arr,
                                  const int* __restrict__ row_ptr,
                                  const int* __restrict__ src_sorted,
                                  const float* __restrict__ bias,
                                  float* __restrict__ outf,
                                  __half* __restrict__ outh,
                                  float* __restrict__ znext_as,
                                  float* __restrict__ znext_ad, int n_nodes) {
    constexpr int R = H * C / 64;
    constexpr int G = 64 / H;
    constexpr int K = H * C;
    __shared__ float lds_e[4][DEG_CAP * H];
    int wave = threadIdx.x >> 6;
    int lane = threadIdx.x & 63;
    int n = blockIdx.x * 4 + wave;
    if (n >= n_nodes) return;
    int beg = row_ptr[n], end = row_ptr[n + 1];
    float* we = lds_e[wave];

    // ---- pass 1: per-head m, l; cache e in LDS ----
    float ad_h[H], m_h[H], l_h[H];
#pragma unroll
    for (int hh = 0; hh < H; hh++) {
        ad_h[hh] = ad_arr[(size_t)n * H + hh];
        m_h[hh] = -INFINITY;
        l_h[hh] = 0.f;
    }
    for (int base = beg; base < end; base += 64) {
        int j = base + lane;
        bool ok = j < end;
        float e_h[H];
        if (ok) {
            int s = src_sorted[j];
            if constexpr (H == 4) {
                float4 a = ((const float4*)as_arr)[s];
                e_h[0] = lrelu(a.x + ad_h[0]);
                e_h[1] = lrelu(a.y + ad_h[1]);
                e_h[2] = lrelu(a.z + ad_h[2]);
                e_h[3] = lrelu(a.w + ad_h[3]);
            } else {
                e_h[0] = lrelu(as_arr[s] + ad_h[0]);
            }
            int idx = j - beg;
            if (idx < DEG_CAP) {
                if constexpr (H == 4) {
                    *(float4*)&we[idx * 4] = make_float4(e_h[0], e_h[1], e_h[2], e_h[3]);
                } else {
                    we[idx] = e_h[0];
                }
            }
        } else {
#pragma unroll
            for (int hh = 0; hh < H; hh++) e_h[hh] = -INFINITY;
        }
#pragma unroll
        for (int hh = 0; hh < H; hh++) {
            float cm = e_h[hh];
#pragma unroll
            for (int off = 1; off < 64; off <<= 1) cm = fmaxf(cm, __shfl_xor(cm, off));
            float newm = fmaxf(m_h[hh], cm);
            float p = ok ? __expf(e_h[hh] - newm) : 0.f;
#pragma unroll
            for (int off = 1; off < 64; off <<= 1) p += __shfl_xor(p, off);
            l_h[hh] = l_h[hh] * __expf(m_h[hh] - newm) + p;
            m_h[hh] = newm;
        }
    }
    int myh = lane / G;
    float mm, adm, inv;
    if constexpr (H == 4) {
        mm  = m_h[0];  mm  = (myh == 1) ? m_h[1] : mm;  mm  = (myh == 2) ? m_h[2] : mm;  mm  = (myh == 3) ? m_h[3] : mm;
        float ll = l_h[0]; ll = (myh == 1) ? l_h[1] : ll; ll = (myh == 2) ? l_h[2] : ll; ll = (myh == 3) ? l_h[3] : ll;
        adm = ad_h[0]; adm = (myh == 1) ? ad_h[1] : adm; adm = (myh == 2) ? ad_h[2] : adm; adm = (myh == 3) ? ad_h[3] : adm;
        inv = 1.f / ll;
    } else {
        mm = m_h[0]; adm = ad_h[0]; inv = 1.f / l_h[0];
    }

    // ---- pass 2: gather, w from cached e (4-edge unroll) ----
    float acc[R];
#pragma unroll
    for (int r = 0; r < R; r++) acc[r] = 0.f;

    int j = beg;
    for (; j + 3 < end; j += 4) {
        int i0 = j - beg;
        int s0 = src_sorted[j];
        int s1 = src_sorted[j + 1];
        int s2 = src_sorted[j + 2];
        int s3 = src_sorted[j + 3];
        float e0, e1, e2, e3;
        if (i0 + 3 < DEG_CAP) {
            e0 = we[(i0 + 0) * H + myh];
            e1 = we[(i0 + 1) * H + myh];
            e2 = we[(i0 + 2) * H + myh];
            e3 = we[(i0 + 3) * H + myh];
        } else {
            e0 = lrelu(as_arr[(size_t)s0 * H + myh] + adm);
            e1 = lrelu(as_arr[(size_t)s1 * H + myh] + adm);
            e2 = lrelu(as_arr[(size_t)s2 * H + myh] + adm);
            e3 = lrelu(as_arr[(size_t)s3 * H + myh] + adm);
        }
        float w0 = __expf(e0 - mm) * inv;
        float w1 = __expf(e1 - mm) * inv;
        float w2 = __expf(e2 - mm) * inv;
        float w3 = __expf(e3 - mm) * inv;
        accum_row<R>(h, (size_t)s0 * K + lane * R, w0, acc);
        accum_row<R>(h, (size_t)s1 * K + lane * R, w1, acc);
        accum_row<R>(h, (size_t)s2 * K + lane * R, w2, acc);
        accum_row<R>(h, (size_t)s3 * K + lane * R, w3, acc);
    }
    for (; j < end; j++) {
        int i0 = j - beg;
        int s0 = src_sorted[j];
        float e0 = (i0 < DEG_CAP) ? we[i0 * H + myh]
                                  : lrelu(as_arr[(size_t)s0 * H + myh] + adm);
        float w0 = __expf(e0 - mm) * inv;
        accum_row<R>(h, (size_t)s0 * K + lane * R, w0, acc);
    }

    // ---- epilogue: bias + relu; zero next layer's as/ad ----
    if (znext_as != nullptr && lane == 0) {
        if constexpr (H == 4) {
            *(float4*)&znext_as[(size_t)n * 4] = make_float4(0.f, 0.f, 0.f, 0.f);
            *(float4*)&znext_ad[(size_t)n * 4] = make_float4(0.f, 0.f, 0.f, 0.f);
        } else {
            znext_as[n] = 0.f;
            znext_ad[n] = 0.f;
        }
    }
    float vout[R];
#pragma unroll
    for (int r = 0; r < R; r++)
        vout[r] = fmaxf(acc[r] + bias[lane * R + r], 0.f);

    if constexpr (F16OUT) {
        unsigned short hv[R];
#pragma unroll
        for (int r = 0; r < R; r++)
            hv[r] = __half_as_ushort(__float2half(vout[r]));
        size_t base = (size_t)n * K + lane * R;
        if constexpr (R == 8) {
            usv8 v = {hv[0], hv[1], hv[2], hv[3], hv[4], hv[5], hv[6], hv[7]};
            *(usv8*)((unsigned short*)outh + base) = v;
        } else if constexpr (R == 4) {
            usv4 v = {hv[0], hv[1], hv[2], hv[3]};
            *(usv4*)((unsigned short*)outh + base) = v;
        } else {
#pragma unroll
            for (int r = 0; r < R; r++) ((unsigned short*)outh)[base + r] = hv[r];
        }
    } else {
#pragma unroll
        for (int r = 0; r < R; r++)
            outf[(size_t)n * K + lane * R + r] = vout[r];
    }
}

// ---------------------------------------------------------------------------

static inline size_t align_up(size_t x) { return (x + 255) & ~(size_t)255; }

extern "C" void kernel_launch(void* const* d_in, const int* in_sizes, int n_in,
                              void* d_out, int out_size, void* d_ws, size_t ws_size,
                              hipStream_t stream) {
    const float* x   = (const float*)d_in[0];
    const int*   ei  = (const int*)d_in[1];
    const float* W1  = (const float*)d_in[2];
    const float* a1s = (const float*)d_in[3];
    const float* a1d = (const float*)d_in[4];
    const float* b1  = (const float*)d_in[5];
    const float* W2  = (const float*)d_in[6];
    const float* a2s = (const float*)d_in[7];
    const float* a2d = (const float*)d_in[8];
    const float* b2  = (const float*)d_in[9];
    const float* W3  = (const float*)d_in[10];
    const float* a3s = (const float*)d_in[11];
    const float* a3d = (const float*)d_in[12];
    const float* b3  = (const float*)d_in[13];
    const float* W4  = (const float*)d_in[14];
    const float* a4s = (const float*)d_in[15];
    const float* a4d = (const float*)d_in[16];
    const float* b4  = (const float*)d_in[17];

    const int n  = in_sizes[0] / 256;    // 30000
    const int e0 = in_sizes[1] / 2;      // 480000
    const int et = e0 + n;
    const int Mpad = ((n + 127) / 128) * 128;   // 30080

    // workspace layout (~100 MB)
    char* w = (char*)d_ws;
    __half* bufA = (__half*)w;                   w += align_up((size_t)Mpad * 512 * 2);
    __half* bufB = (__half*)w;                   w += align_up((size_t)Mpad * 512 * 2);
    __half* hbuf = (__half*)w;                   w += align_up((size_t)Mpad * 512 * 2);
    __half* WT1 = (__half*)w;                    w += align_up((size_t)512 * 256 * 2);
    __half* WT2 = (__half*)w;                    w += align_up((size_t)512 * 512 * 2);
    __half* WT3 = (__half*)w;                    w += align_up((size_t)256 * 512 * 2);
    __half* WT4 = (__half*)w;                    w += align_up((size_t)128 * 256 * 2);
    float* asA = (float*)w;                      w += align_up((size_t)n * 4 * 4);
    float* adA = (float*)w;                      w += align_up((size_t)n * 4 * 4);
    float* asB = (float*)w;                      w += align_up((size_t)n * 4 * 4);
    float* adB = (float*)w;                      w += align_up((size_t)n * 4 * 4);
    int* row_ptr = (int*)w;                      w += align_up((size_t)(n + 1) * 4);
    int* counts  = (int*)w;                      w += align_up((size_t)n * 4);
    int* cursor  = (int*)w;                      w += align_up((size_t)n * 4);
    int* src_sorted = (int*)w;                   w += align_up((size_t)et * 4);
    (void)ws_size;

    dim3 blk(256);
    int nodeblocks = (n + 3) / 4;

    // ---- CSR build ----
    zero_int<<<(n + 255) / 256, 256, 0, stream>>>(counts, n);
    hist_kernel<<<(et + 255) / 256, 256, 0, stream>>>(ei, e0, n, counts);
    scan_kernel<<<1, 1024, 0, stream>>>(counts, row_ptr, cursor, n);
    scatter_kernel<<<(et + 255) / 256, 256, 0, stream>>>(ei, e0, n, cursor, src_sorted);

    // ---- fused conversion prologue (x + 4 weights + as/ad zero) ----
    const int nx = n * 256;
    conv_all<<<(nx + 557056 + n * 8 + 255) / 256, blk, 0, stream>>>(
        x, bufA, nx, W1, WT1, W2, WT2, W3, WT3, W4, WT4, asA, n * 8);

    const int mblocks = Mpad / 128;   // 235

    // ---- Layer 1: K=256 -> N=512 (4 heads x 128) ----
    gemm_mfma<<<dim3(4 * mblocks), blk, 0, stream>>>(bufA, WT1, hbuf, n, 256, 512, 4, mblocks,
                                                     a1s, a1d, asA, adA, 4, 128);
    agg_kernel<4, 128, true><<<nodeblocks, blk, 0, stream>>>(hbuf, asA, adA, row_ptr, src_sorted, b1, nullptr, bufB, asB, adB, n);

    // ---- Layer 2: K=512 -> N=512 ----
    gemm_mfma<<<dim3(4 * mblocks), blk, 0, stream>>>(bufB, WT2, hbuf, n, 512, 512, 4, mblocks,
                                                     a2s, a2d, asB, adB, 4, 128);
    agg_kernel<4, 128, true><<<nodeblocks, blk, 0, stream>>>(hbuf, asB, adB, row_ptr, src_sorted, b2, nullptr, bufA, asA, adA, n);

    // ---- Layer 3: K=512 -> N=256 (4 heads x 64) ----
    gemm_mfma<<<dim3(2 * mblocks), blk, 0, stream>>>(bufA, WT3, hbuf, n, 512, 256, 2, mblocks,
                                                     a3s, a3d, asA, adA, 4, 64);
    agg_kernel<4, 64, true><<<nodeblocks, blk, 0, stream>>>(hbuf, asA, adA, row_ptr, src_sorted, b3, nullptr, bufB, asB, adB, n);

    // ---- Layer 4: K=256 -> N=64, 1 head ----
    gemm_mfma<<<dim3(1 * mblocks), blk, 0, stream>>>(bufB, WT4, hbuf, n, 256, 64, 1, mblocks,
                                                     a4s, a4d, asB, adB, 1, 64);
    agg_kernel<1, 64, false><<<nodeblocks, blk, 0, stream>>>(hbuf, asB, adB, row_ptr, src_sorted, b4, (float*)d_out, nullptr, nullptr, nullptr, n);
}